// Round 2
// baseline (65282.269 us; speedup 1.0000x reference)
//
#include <hip/hip_runtime.h>

// Persistent fused 2-layer LSTM + FC + softmax for MI355X.
// B=2048 rows, T=256 steps, H=64, IN=42. 256 blocks x 256 threads;
// each block owns 8 batch rows end-to-end (no inter-block traffic).
// lane = (row r = tid&7, gate-chunk gc = tid>>3): 8 gate rows per lane.
// Weights stream from L2 via per-lane vector loads (8-way same-address
// merge across row-lanes); h/x broadcast from LDS (1 b128 per 8 FMAs).

namespace {
constexpr int kB = 2048;
constexpr int kT = 256;
constexpr int kIn = 42;
constexpr int kH = 64;
constexpr int kRows = 8;    // batch rows per block
constexpr int kThr = 256;
constexpr int kXPad = 44;   // xs row stride (floats)
constexpr int kHPad = 68;   // h row stride: r*68*4B = 16B-aligned, banks spread
constexpr int kGPad = 260;  // gate-buf row stride: breaks 256-stride conflicts
}

__device__ __forceinline__ float sig_(float v) {
  return __fdividef(1.0f, 1.0f + __expf(-v));
}
__device__ __forceinline__ float tnh_(float v) {
  return __fdividef(2.0f, 1.0f + __expf(-2.0f * v)) - 1.0f;
}

__global__ __launch_bounds__(kThr, 1)
void lstm_fused_kernel(const float* __restrict__ x,
                       const float* __restrict__ Wih0, const float* __restrict__ Whh0,
                       const float* __restrict__ bih0, const float* __restrict__ bhh0,
                       const float* __restrict__ Wih1, const float* __restrict__ Whh1,
                       const float* __restrict__ bih1, const float* __restrict__ bhh1,
                       const float* __restrict__ Wfc, const float* __restrict__ bfc,
                       float* __restrict__ out) {
  __shared__ float xs[kRows * kXPad];
  __shared__ float hb0[kRows * kHPad];
  __shared__ float hb1[kRows * kHPad];
  __shared__ float gsm[kRows * kGPad];
  __shared__ float lg[kRows * 8];

  const int tid = threadIdx.x;
  const int r = tid & 7;          // row within block for gate-accum role
  const int gc = tid >> 3;        // gate chunk 0..31
  const int k0 = gc * 8;          // first of this lane's 8 gate rows
  const int row0 = blockIdx.x * kRows;

  for (int i = tid; i < kRows * kHPad; i += kThr) { hb0[i] = 0.f; hb1[i] = 0.f; }

  // combined biases (b_ih + b_hh) for this lane's gate rows
  float b0[8], b1[8];
#pragma unroll
  for (int gi = 0; gi < 8; ++gi) {
    b0[gi] = bih0[k0 + gi] + bhh0[k0 + gi];
    b1[gi] = bih1[k0 + gi] + bhh1[k0 + gi];
  }

  const float* w0i = Wih0 + (size_t)k0 * kIn;
  const float* w0h = Whh0 + (size_t)k0 * kH;
  const float* w1i = Wih1 + (size_t)k0 * kH;
  const float* w1h = Whh1 + (size_t)k0 * kH;

  // update-role mapping: tasks u=tid (row ur) and u=tid+256 (row ur+4), dim uj
  const int ur = tid >> 6;        // 0..3
  const int uj = tid & 63;
  float c0a = 0.f, c0b = 0.f, c1a = 0.f, c1b = 0.f;

  const float* xrow = x + (size_t)row0 * kT * kIn;

  for (int t = 0; t < kT; ++t) {
    // stage x[:, t, :] for our 8 rows into LDS
    for (int i = tid; i < kRows * kIn; i += kThr) {
      int rr = i / kIn;
      int dd = i - rr * kIn;
      xs[rr * kXPad + dd] = xrow[(size_t)rr * kT * kIn + (size_t)t * kIn + dd];
    }
    __syncthreads();  // A: xs ready

    // ---------------- layer 0 gate pre-activations ----------------
    float acc[8];
#pragma unroll
    for (int gi = 0; gi < 8; ++gi) acc[gi] = b0[gi];
    // input part (42 dims, float2: rows are only 8B-aligned)
#pragma unroll
    for (int j2 = 0; j2 < kIn / 2; ++j2) {
      const float2 xv = *(const float2*)&xs[r * kXPad + j2 * 2];
#pragma unroll
      for (int gi = 0; gi < 8; ++gi) {
        const float2 wv = *(const float2*)&w0i[gi * kIn + j2 * 2];
        acc[gi] += wv.x * xv.x + wv.y * xv.y;
      }
    }
    // recurrent part (64 dims, float4)
#pragma unroll
    for (int j4 = 0; j4 < kH / 4; ++j4) {
      const float4 hv = *(const float4*)&hb0[r * kHPad + j4 * 4];
#pragma unroll
      for (int gi = 0; gi < 8; ++gi) {
        const float4 wv = *(const float4*)&w0h[gi * kH + j4 * 4];
        acc[gi] += wv.x * hv.x + wv.y * hv.y + wv.z * hv.z + wv.w * hv.w;
      }
    }
#pragma unroll
    for (int gi = 0; gi < 8; ++gi) gsm[r * kGPad + k0 + gi] = acc[gi];
    __syncthreads();  // B: gates ready, hb0 reads done

    // ---------------- layer 0 cell/hidden update ----------------
    {
      float gi_ = gsm[ur * kGPad + uj];
      float gf_ = gsm[ur * kGPad + 64 + uj];
      float gg_ = gsm[ur * kGPad + 128 + uj];
      float go_ = gsm[ur * kGPad + 192 + uj];
      c0a = sig_(gf_) * c0a + sig_(gi_) * tnh_(gg_);
      hb0[ur * kHPad + uj] = sig_(go_) * tnh_(c0a);
      const int r2 = ur + 4;
      gi_ = gsm[r2 * kGPad + uj];
      gf_ = gsm[r2 * kGPad + 64 + uj];
      gg_ = gsm[r2 * kGPad + 128 + uj];
      go_ = gsm[r2 * kGPad + 192 + uj];
      c0b = sig_(gf_) * c0b + sig_(gi_) * tnh_(gg_);
      hb0[r2 * kHPad + uj] = sig_(go_) * tnh_(c0b);
    }
    __syncthreads();  // C: new hb0 visible, gsm reads done

    // ---------------- layer 1 gate pre-activations ----------------
#pragma unroll
    for (int gi = 0; gi < 8; ++gi) acc[gi] = b1[gi];
#pragma unroll
    for (int j4 = 0; j4 < kH / 4; ++j4) {
      const float4 hv = *(const float4*)&hb0[r * kHPad + j4 * 4];
#pragma unroll
      for (int gi = 0; gi < 8; ++gi) {
        const float4 wv = *(const float4*)&w1i[gi * kH + j4 * 4];
        acc[gi] += wv.x * hv.x + wv.y * hv.y + wv.z * hv.z + wv.w * hv.w;
      }
    }
#pragma unroll
    for (int j4 = 0; j4 < kH / 4; ++j4) {
      const float4 hv = *(const float4*)&hb1[r * kHPad + j4 * 4];
#pragma unroll
      for (int gi = 0; gi < 8; ++gi) {
        const float4 wv = *(const float4*)&w1h[gi * kH + j4 * 4];
        acc[gi] += wv.x * hv.x + wv.y * hv.y + wv.z * hv.z + wv.w * hv.w;
      }
    }
#pragma unroll
    for (int gi = 0; gi < 8; ++gi) gsm[r * kGPad + k0 + gi] = acc[gi];
    __syncthreads();  // D

    // ---------------- layer 1 cell/hidden update ----------------
    {
      float gi_ = gsm[ur * kGPad + uj];
      float gf_ = gsm[ur * kGPad + 64 + uj];
      float gg_ = gsm[ur * kGPad + 128 + uj];
      float go_ = gsm[ur * kGPad + 192 + uj];
      c1a = sig_(gf_) * c1a + sig_(gi_) * tnh_(gg_);
      hb1[ur * kHPad + uj] = sig_(go_) * tnh_(c1a);
      const int r2 = ur + 4;
      gi_ = gsm[r2 * kGPad + uj];
      gf_ = gsm[r2 * kGPad + 64 + uj];
      gg_ = gsm[r2 * kGPad + 128 + uj];
      go_ = gsm[r2 * kGPad + 192 + uj];
      c1b = sig_(gf_) * c1b + sig_(gi_) * tnh_(gg_);   // fixed: was tnh_(c1b)
      hb1[r2 * kHPad + uj] = sig_(go_) * tnh_(c1b);
    }
    __syncthreads();  // E: hb1 visible; gsm/xs free for next step
  }

  // ---------------- FC + softmax (final h1 in hb1) ----------------
  if (tid < kRows * 5) {
    const int rr = tid / 5;
    const int oo = tid - rr * 5;
    float a = bfc[oo];
#pragma unroll
    for (int j = 0; j < kH; ++j) a += hb1[rr * kHPad + j] * Wfc[oo * kH + j];
    lg[rr * 8 + oo] = a;
  }
  __syncthreads();
  if (tid < kRows) {
    const float v0 = lg[tid * 8 + 0], v1 = lg[tid * 8 + 1], v2 = lg[tid * 8 + 2],
                v3 = lg[tid * 8 + 3], v4 = lg[tid * 8 + 4];
    const float m = fmaxf(fmaxf(fmaxf(v0, v1), fmaxf(v2, v3)), v4);
    const float e0 = __expf(v0 - m), e1 = __expf(v1 - m), e2 = __expf(v2 - m),
                e3 = __expf(v3 - m), e4 = __expf(v4 - m);
    const float inv = __fdividef(1.0f, e0 + e1 + e2 + e3 + e4);
    float* o = out + (size_t)(row0 + tid) * 5;
    o[0] = e0 * inv; o[1] = e1 * inv; o[2] = e2 * inv; o[3] = e3 * inv; o[4] = e4 * inv;
  }
}

extern "C" void kernel_launch(void* const* d_in, const int* in_sizes, int n_in,
                              void* d_out, int out_size, void* d_ws, size_t ws_size,
                              hipStream_t stream) {
  (void)in_sizes; (void)n_in; (void)d_ws; (void)ws_size; (void)out_size;
  lstm_fused_kernel<<<dim3(kB / kRows), dim3(kThr), 0, stream>>>(
      (const float*)d_in[0],
      (const float*)d_in[1], (const float*)d_in[2],
      (const float*)d_in[3], (const float*)d_in[4],
      (const float*)d_in[5], (const float*)d_in[6],
      (const float*)d_in[7], (const float*)d_in[8],
      (const float*)d_in[9], (const float*)d_in[10],
      (float*)d_out);
}

// Round 3
// 6612.503 us; speedup vs baseline: 9.8726x; 9.8726x over previous
//
#include <hip/hip_runtime.h>

// Persistent fused 2-layer LSTM + FC + softmax for MI355X.
// B=2048 rows, T=256 steps, H=64, IN=42. 256 blocks x 256 threads;
// each block owns 8 batch rows end-to-end (no inter-block traffic).
// lane = (row r = tid&7, gate-chunk gc = tid>>3): 8 gate rows per lane.
// Weights stream from L1/L2 via per-lane vector loads (8-way same-address
// merge across row-lanes); h/x broadcast from LDS (1 b128 per 8 FMAs).
//
// R2 lesson: weight loads are t-invariant; with __restrict__ LICM hoisted
// ~1872 floats/thread, spilled to scratch -> 68 GB HBM spill traffic, 65 ms.
// Fix: launder weight pointers through asm volatile inside the t-loop so
// the address is opaque per-iteration (loads cannot be hoisted), and cap
// unroll to keep register pressure low.

namespace {
constexpr int kB = 2048;
constexpr int kT = 256;
constexpr int kIn = 42;
constexpr int kH = 64;
constexpr int kRows = 8;    // batch rows per block
constexpr int kThr = 256;
constexpr int kXPad = 44;   // xs row stride (floats)
constexpr int kHPad = 68;   // h row stride: r*68*4B = 16B-aligned, banks spread
constexpr int kGPad = 260;  // gate-buf row stride: breaks 256-stride conflicts
}

__device__ __forceinline__ float sig_(float v) {
  return __fdividef(1.0f, 1.0f + __expf(-v));
}
__device__ __forceinline__ float tnh_(float v) {
  return __fdividef(2.0f, 1.0f + __expf(-2.0f * v)) - 1.0f;
}

__global__ __launch_bounds__(kThr, 1)
void lstm_fused_kernel(const float* __restrict__ x,
                       const float* __restrict__ Wih0, const float* __restrict__ Whh0,
                       const float* __restrict__ bih0, const float* __restrict__ bhh0,
                       const float* __restrict__ Wih1, const float* __restrict__ Whh1,
                       const float* __restrict__ bih1, const float* __restrict__ bhh1,
                       const float* __restrict__ Wfc, const float* __restrict__ bfc,
                       float* __restrict__ out) {
  __shared__ float xs[kRows * kXPad];
  __shared__ float hb0[kRows * kHPad];
  __shared__ float hb1[kRows * kHPad];
  __shared__ float gsm[kRows * kGPad];
  __shared__ float lg[kRows * 8];

  const int tid = threadIdx.x;
  const int r = tid & 7;          // row within block for gate-accum role
  const int gc = tid >> 3;        // gate chunk 0..31
  const int k0 = gc * 8;          // first of this lane's 8 gate rows
  const int row0 = blockIdx.x * kRows;

  for (int i = tid; i < kRows * kHPad; i += kThr) { hb0[i] = 0.f; hb1[i] = 0.f; }

  // combined biases (b_ih + b_hh) for this lane's gate rows
  float b0[8], b1[8];
#pragma unroll
  for (int gi = 0; gi < 8; ++gi) {
    b0[gi] = bih0[k0 + gi] + bhh0[k0 + gi];
    b1[gi] = bih1[k0 + gi] + bhh1[k0 + gi];
  }

  // per-lane weight base pointers; laundered every t-iteration below
  const float* w0i = Wih0 + (size_t)k0 * kIn;
  const float* w0h = Whh0 + (size_t)k0 * kH;
  const float* w1i = Wih1 + (size_t)k0 * kH;
  const float* w1h = Whh1 + (size_t)k0 * kH;

  // update-role mapping: tasks u=tid (row ur) and u=tid+256 (row ur+4), dim uj
  const int ur = tid >> 6;        // 0..3
  const int uj = tid & 63;
  float c0a = 0.f, c0b = 0.f, c1a = 0.f, c1b = 0.f;

  const float* xrow = x + (size_t)row0 * kT * kIn;

  for (int t = 0; t < kT; ++t) {
    // Launder weight pointers: value is opaque per-iteration, so the
    // compiler cannot hoist (LICM) or CSE the t-invariant weight loads —
    // that hoist spilled ~8 KB/thread to scratch and cost 68 GB of HBM
    // traffic in R2.
    asm volatile("" : "+v"(w0i), "+v"(w0h), "+v"(w1i), "+v"(w1h));

    // stage x[:, t, :] for our 8 rows into LDS
    for (int i = tid; i < kRows * kIn; i += kThr) {
      int rr = i / kIn;
      int dd = i - rr * kIn;
      xs[rr * kXPad + dd] = xrow[(size_t)rr * kT * kIn + (size_t)t * kIn + dd];
    }
    __syncthreads();  // A: xs ready

    // ---------------- layer 0 gate pre-activations ----------------
    float acc[8];
#pragma unroll
    for (int gi = 0; gi < 8; ++gi) acc[gi] = b0[gi];
    // input part (42 dims, float2: rows are only 8B-aligned)
#pragma unroll 3
    for (int j2 = 0; j2 < kIn / 2; ++j2) {
      const float2 xv = *(const float2*)&xs[r * kXPad + j2 * 2];
#pragma unroll
      for (int gi = 0; gi < 8; ++gi) {
        const float2 wv = *(const float2*)&w0i[gi * kIn + j2 * 2];
        acc[gi] += wv.x * xv.x + wv.y * xv.y;
      }
    }
    // recurrent part (64 dims, float4)
#pragma unroll 4
    for (int j4 = 0; j4 < kH / 4; ++j4) {
      const float4 hv = *(const float4*)&hb0[r * kHPad + j4 * 4];
#pragma unroll
      for (int gi = 0; gi < 8; ++gi) {
        const float4 wv = *(const float4*)&w0h[gi * kH + j4 * 4];
        acc[gi] += wv.x * hv.x + wv.y * hv.y + wv.z * hv.z + wv.w * hv.w;
      }
    }
#pragma unroll
    for (int gi = 0; gi < 8; ++gi) gsm[r * kGPad + k0 + gi] = acc[gi];
    __syncthreads();  // B: gates ready, hb0 reads done

    // ---------------- layer 0 cell/hidden update ----------------
    {
      float gi_ = gsm[ur * kGPad + uj];
      float gf_ = gsm[ur * kGPad + 64 + uj];
      float gg_ = gsm[ur * kGPad + 128 + uj];
      float go_ = gsm[ur * kGPad + 192 + uj];
      c0a = sig_(gf_) * c0a + sig_(gi_) * tnh_(gg_);
      hb0[ur * kHPad + uj] = sig_(go_) * tnh_(c0a);
      const int r2 = ur + 4;
      gi_ = gsm[r2 * kGPad + uj];
      gf_ = gsm[r2 * kGPad + 64 + uj];
      gg_ = gsm[r2 * kGPad + 128 + uj];
      go_ = gsm[r2 * kGPad + 192 + uj];
      c0b = sig_(gf_) * c0b + sig_(gi_) * tnh_(gg_);
      hb0[r2 * kHPad + uj] = sig_(go_) * tnh_(c0b);
    }
    __syncthreads();  // C: new hb0 visible, gsm reads done

    // ---------------- layer 1 gate pre-activations ----------------
#pragma unroll
    for (int gi = 0; gi < 8; ++gi) acc[gi] = b1[gi];
#pragma unroll 4
    for (int j4 = 0; j4 < kH / 4; ++j4) {
      const float4 hv = *(const float4*)&hb0[r * kHPad + j4 * 4];
#pragma unroll
      for (int gi = 0; gi < 8; ++gi) {
        const float4 wv = *(const float4*)&w1i[gi * kH + j4 * 4];
        acc[gi] += wv.x * hv.x + wv.y * hv.y + wv.z * hv.z + wv.w * hv.w;
      }
    }
#pragma unroll 4
    for (int j4 = 0; j4 < kH / 4; ++j4) {
      const float4 hv = *(const float4*)&hb1[r * kHPad + j4 * 4];
#pragma unroll
      for (int gi = 0; gi < 8; ++gi) {
        const float4 wv = *(const float4*)&w1h[gi * kH + j4 * 4];
        acc[gi] += wv.x * hv.x + wv.y * hv.y + wv.z * hv.z + wv.w * hv.w;
      }
    }
#pragma unroll
    for (int gi = 0; gi < 8; ++gi) gsm[r * kGPad + k0 + gi] = acc[gi];
    __syncthreads();  // D

    // ---------------- layer 1 cell/hidden update ----------------
    {
      float gi_ = gsm[ur * kGPad + uj];
      float gf_ = gsm[ur * kGPad + 64 + uj];
      float gg_ = gsm[ur * kGPad + 128 + uj];
      float go_ = gsm[ur * kGPad + 192 + uj];
      c1a = sig_(gf_) * c1a + sig_(gi_) * tnh_(gg_);
      hb1[ur * kHPad + uj] = sig_(go_) * tnh_(c1a);
      const int r2 = ur + 4;
      gi_ = gsm[r2 * kGPad + uj];
      gf_ = gsm[r2 * kGPad + 64 + uj];
      gg_ = gsm[r2 * kGPad + 128 + uj];
      go_ = gsm[r2 * kGPad + 192 + uj];
      c1b = sig_(gf_) * c1b + sig_(gi_) * tnh_(gg_);
      hb1[r2 * kHPad + uj] = sig_(go_) * tnh_(c1b);
    }
    __syncthreads();  // E: hb1 visible; gsm/xs free for next step
  }

  // ---------------- FC + softmax (final h1 in hb1) ----------------
  if (tid < kRows * 5) {
    const int rr = tid / 5;
    const int oo = tid - rr * 5;
    float a = bfc[oo];
#pragma unroll
    for (int j = 0; j < kH; ++j) a += hb1[rr * kHPad + j] * Wfc[oo * kH + j];
    lg[rr * 8 + oo] = a;
  }
  __syncthreads();
  if (tid < kRows) {
    const float v0 = lg[tid * 8 + 0], v1 = lg[tid * 8 + 1], v2 = lg[tid * 8 + 2],
                v3 = lg[tid * 8 + 3], v4 = lg[tid * 8 + 4];
    const float m = fmaxf(fmaxf(fmaxf(v0, v1), fmaxf(v2, v3)), v4);
    const float e0 = __expf(v0 - m), e1 = __expf(v1 - m), e2 = __expf(v2 - m),
                e3 = __expf(v3 - m), e4 = __expf(v4 - m);
    const float inv = __fdividef(1.0f, e0 + e1 + e2 + e3 + e4);
    float* o = out + (size_t)(row0 + tid) * 5;
    o[0] = e0 * inv; o[1] = e1 * inv; o[2] = e2 * inv; o[3] = e3 * inv; o[4] = e4 * inv;
  }
}

extern "C" void kernel_launch(void* const* d_in, const int* in_sizes, int n_in,
                              void* d_out, int out_size, void* d_ws, size_t ws_size,
                              hipStream_t stream) {
  (void)in_sizes; (void)n_in; (void)d_ws; (void)ws_size; (void)out_size;
  lstm_fused_kernel<<<dim3(kB / kRows), dim3(kThr), 0, stream>>>(
      (const float*)d_in[0],
      (const float*)d_in[1], (const float*)d_in[2],
      (const float*)d_in[3], (const float*)d_in[4],
      (const float*)d_in[5], (const float*)d_in[6],
      (const float*)d_in[7], (const float*)d_in[8],
      (const float*)d_in[9], (const float*)d_in[10],
      (float*)d_out);
}

// Round 5
// 1237.726 us; speedup vs baseline: 52.7437x; 5.3425x over previous
//
#include <hip/hip_runtime.h>

// Persistent fused 2-layer LSTM + FC + softmax for MI355X (gfx950).
// B=2048, T=256, H=64, IN=42. 256 blocks x 256 threads; block owns 8 rows.
//
// R3 lesson: streaming 234 KB/step of fp32 weights from L2 is VMEM-request
// bound (62K cyc/step, VALUBusy 19%). Fix: weights RESIDENT IN VGPRs as f16
// (234 f16 = 117 dwords/lane), h/x in LDS as f16, v_dot2_f32_f16 (2 MAC/instr,
// fp32 accumulate). Cross-lane k-reduction via quad_perm DPP (VALU-only).
// fp32 state (c, gates, softmax) throughout; only GEMM operands are f16.
//
// lane = (kc = tid&3: 32-wide k-chunk, gg = tid>>2: 4 gate rows gg*4..gg*4+3).
// K padded to 128: L0 k-space = [x(42) | h0(64) | 0(22)]; L1 = [h0(64) | h1(64)].
//
// R4 fix: __builtin_amdgcn_update_dpp needs a compile-time dpp_ctrl ->
// template parameter instead of runtime arg.

typedef _Float16 f16;
typedef _Float16 f16x2 __attribute__((ext_vector_type(2)));

namespace {
constexpr int kT = 256;
constexpr int kIn = 42;
constexpr int kH = 64;
constexpr int kRows = 8;
constexpr int kThr = 256;
constexpr int kK = 128;   // padded K (f16 elems); row = 256 B, 16B-aligned
constexpr int kGs = 256;  // gsm row stride (dwords)
}

__device__ __forceinline__ float sig_(float v) {
  return __fdividef(1.0f, 1.0f + __expf(-v));
}
__device__ __forceinline__ float tnh_(float v) {
  return __fdividef(2.0f, 1.0f + __expf(-2.0f * v)) - 1.0f;
}

// butterfly add across quad lanes: ctrl 0xB1 = quad_perm[1,0,3,2] (xor1),
// 0x4E = quad_perm[2,3,0,1] (xor2). VALU-only, no DS pipe.
template <int kCtrl>
__device__ __forceinline__ float dpp_add(float v) {
  int s = __builtin_amdgcn_update_dpp(0, __builtin_bit_cast(int, v), kCtrl, 0xF, 0xF, false);
  return v + __builtin_bit_cast(float, s);
}

#if defined(__has_builtin)
#if __has_builtin(__builtin_amdgcn_fdot2)
#define HAVE_FDOT2 1
#endif
#endif

__device__ __forceinline__ float dot2_(f16x2 a, f16x2 b, float c) {
#ifdef HAVE_FDOT2
  return __builtin_amdgcn_fdot2(a, b, c, false);
#else
  return c + (float)a.x * (float)b.x + (float)a.y * (float)b.y;
#endif
}

__device__ __forceinline__ f16x2 bcast_(float v) {
  return __builtin_bit_cast(f16x2, v);
}

// one layer's gate GEMM: gsm[r][tid] = bias + sum_k w[g][k] * xh[r][k]
__device__ __forceinline__ void gemm_phase(const f16* __restrict__ xh,
                                           const f16x2 (&w)[4][16],
                                           float bias, float* __restrict__ gsm,
                                           int kc, int tid) {
#pragma unroll
  for (int r = 0; r < kRows; ++r) {
    const float4* hp = (const float4*)(xh + r * kK + kc * 32);
    float4 q0 = hp[0], q1 = hp[1], q2 = hp[2], q3 = hp[3];
    f16x2 hh[16];
    hh[0] = bcast_(q0.x); hh[1] = bcast_(q0.y); hh[2] = bcast_(q0.z); hh[3] = bcast_(q0.w);
    hh[4] = bcast_(q1.x); hh[5] = bcast_(q1.y); hh[6] = bcast_(q1.z); hh[7] = bcast_(q1.w);
    hh[8] = bcast_(q2.x); hh[9] = bcast_(q2.y); hh[10] = bcast_(q2.z); hh[11] = bcast_(q2.w);
    hh[12] = bcast_(q3.x); hh[13] = bcast_(q3.y); hh[14] = bcast_(q3.z); hh[15] = bcast_(q3.w);
    float a0 = 0.f, a1 = 0.f, a2 = 0.f, a3 = 0.f;
#pragma unroll
    for (int m = 0; m < 16; ++m) {
      a0 = dot2_(w[0][m], hh[m], a0);
      a1 = dot2_(w[1][m], hh[m], a1);
      a2 = dot2_(w[2][m], hh[m], a2);
      a3 = dot2_(w[3][m], hh[m], a3);
    }
    // full k-sum lands in all 4 quad lanes
    a0 = dpp_add<0x4E>(dpp_add<0xB1>(a0));
    a1 = dpp_add<0x4E>(dpp_add<0xB1>(a1));
    a2 = dpp_add<0x4E>(dpp_add<0xB1>(a2));
    a3 = dpp_add<0x4E>(dpp_add<0xB1>(a3));
    // lane kc writes gate row gg*4+kc == tid  (contiguous per wave)
    float s01 = (kc & 1) ? a1 : a0;
    float s23 = (kc & 1) ? a3 : a2;
    float val = (kc & 2) ? s23 : s01;
    gsm[r * kGs + tid] = val + bias;
  }
}

__global__ __launch_bounds__(kThr, 1)
void lstm_f16reg_kernel(const float* __restrict__ x,
                        const float* __restrict__ Wih0, const float* __restrict__ Whh0,
                        const float* __restrict__ bih0, const float* __restrict__ bhh0,
                        const float* __restrict__ Wih1, const float* __restrict__ Whh1,
                        const float* __restrict__ bih1, const float* __restrict__ bhh1,
                        const float* __restrict__ Wfc, const float* __restrict__ bfc,
                        float* __restrict__ out) {
  __shared__ __align__(16) f16 xh0[kRows * kK];  // [x(42) | h0(64) | zeros]
  __shared__ __align__(16) f16 xh1[kRows * kK];  // [h0(64) | h1(64)]
  __shared__ float gsm[kRows * kGs];
  __shared__ float lg[kRows * 8];

  const int tid = threadIdx.x;
  const int kc = tid & 3;
  const int gg = tid >> 2;
  const int row0 = blockIdx.x * kRows;

  // zero both staging buffers (covers h=0 init and k-padding)
  for (int i = tid; i < kRows * kK; i += kThr) {
    xh0[i] = (f16)0; xh1[i] = (f16)0;
  }

  // ---- one-time: load this lane's weights into registers as f16 ----
  f16x2 w0[4][16], w1[4][16];
#pragma unroll
  for (int j = 0; j < 4; ++j) {
    const int g = gg * 4 + j;
#pragma unroll
    for (int m = 0; m < 16; ++m) {
      const int s0 = kc * 32 + 2 * m, s1 = s0 + 1;
      float l0 = (s0 < 42) ? Wih0[g * kIn + s0] : (s0 < 106 ? Whh0[g * kH + s0 - 42] : 0.f);
      float h0 = (s1 < 42) ? Wih0[g * kIn + s1] : (s1 < 106 ? Whh0[g * kH + s1 - 42] : 0.f);
      f16x2 v0; v0.x = (f16)l0; v0.y = (f16)h0;
      w0[j][m] = v0;
      float l1 = (s0 < 64) ? Wih1[g * kH + s0] : Whh1[g * kH + s0 - 64];
      float h1 = (s1 < 64) ? Wih1[g * kH + s1] : Whh1[g * kH + s1 - 64];
      f16x2 v1; v1.x = (f16)l1; v1.y = (f16)h1;
      w1[j][m] = v1;
    }
  }
  // combined bias for the gate row this lane WRITES (gg*4+kc == tid)
  const float bb0 = bih0[tid] + bhh0[tid];
  const float bb1 = bih1[tid] + bhh1[tid];

  // update roles: tasks u=tid (r=ur, j=uj) and u=tid+256 (r=ur+4)
  const int ur = tid >> 6;
  const int uj = tid & 63;
  float c0a = 0.f, c0b = 0.f, c1a = 0.f, c1b = 0.f;

  const float* xbase = x + (size_t)row0 * kT * kIn;

  // stage x[:, t, :] (8 rows x 42) as f16 pairs; 168 threads, 1 float2 each
  auto stage_x = [&](int t) {
    if (tid < 168) {
      const int rr = tid / 21, p = tid - rr * 21;
      const float2 v = *(const float2*)(xbase + (size_t)rr * kT * kIn + (size_t)t * kIn + 2 * p);
      f16x2 hv; hv.x = (f16)v.x; hv.y = (f16)v.y;
      *(f16x2*)&xh0[rr * kK + 2 * p] = hv;
    }
  };

  stage_x(0);
  __syncthreads();

  for (int t = 0; t < kT; ++t) {
    // ---- layer 0 gates: read [x | h0] from xh0 ----
    gemm_phase(xh0, w0, bb0, gsm, kc, tid);
    __syncthreads();  // B: gsm ready; xh0 reads done

    // ---- layer 0 update (fp32), h0 -> xh0[42+j] and xh1[j] ----
    {
      float gi = gsm[ur * kGs + uj], gf = gsm[ur * kGs + 64 + uj];
      float gG = gsm[ur * kGs + 128 + uj], go = gsm[ur * kGs + 192 + uj];
      c0a = sig_(gf) * c0a + sig_(gi) * tnh_(gG);
      f16 hh = (f16)(sig_(go) * tnh_(c0a));
      xh0[ur * kK + 42 + uj] = hh; xh1[ur * kK + uj] = hh;
      const int r2 = ur + 4;
      gi = gsm[r2 * kGs + uj]; gf = gsm[r2 * kGs + 64 + uj];
      gG = gsm[r2 * kGs + 128 + uj]; go = gsm[r2 * kGs + 192 + uj];
      c0b = sig_(gf) * c0b + sig_(gi) * tnh_(gG);
      f16 hh2 = (f16)(sig_(go) * tnh_(c0b));
      xh0[r2 * kK + 42 + uj] = hh2; xh1[r2 * kK + uj] = hh2;
    }
    if (t + 1 < kT) stage_x(t + 1);  // x region of xh0 is dead until next gemm
    __syncthreads();  // C: h0/x staged; gsm reads done

    // ---- layer 1 gates: read [h0 | h1] from xh1 ----
    gemm_phase(xh1, w1, bb1, gsm, kc, tid);
    __syncthreads();  // D

    // ---- layer 1 update, h1 -> xh1[64+j] ----
    {
      float gi = gsm[ur * kGs + uj], gf = gsm[ur * kGs + 64 + uj];
      float gG = gsm[ur * kGs + 128 + uj], go = gsm[ur * kGs + 192 + uj];
      c1a = sig_(gf) * c1a + sig_(gi) * tnh_(gG);
      xh1[ur * kK + 64 + uj] = (f16)(sig_(go) * tnh_(c1a));
      const int r2 = ur + 4;
      gi = gsm[r2 * kGs + uj]; gf = gsm[r2 * kGs + 64 + uj];
      gG = gsm[r2 * kGs + 128 + uj]; go = gsm[r2 * kGs + 192 + uj];
      c1b = sig_(gf) * c1b + sig_(gi) * tnh_(gG);
      xh1[r2 * kK + 64 + uj] = (f16)(sig_(go) * tnh_(c1b));
    }
    __syncthreads();  // E
  }

  // ---- FC + softmax (final h1 in xh1[.][64..127]) ----
  if (tid < kRows * 5) {
    const int rr = tid / 5, oo = tid - rr * 5;
    float a = bfc[oo];
#pragma unroll
    for (int j = 0; j < kH; ++j)
      a += (float)xh1[rr * kK + 64 + j] * Wfc[oo * kH + j];
    lg[rr * 8 + oo] = a;
  }
  __syncthreads();
  if (tid < kRows) {
    const float v0 = lg[tid * 8 + 0], v1 = lg[tid * 8 + 1], v2 = lg[tid * 8 + 2],
                v3 = lg[tid * 8 + 3], v4 = lg[tid * 8 + 4];
    const float m = fmaxf(fmaxf(fmaxf(v0, v1), fmaxf(v2, v3)), v4);
    const float e0 = __expf(v0 - m), e1 = __expf(v1 - m), e2 = __expf(v2 - m),
                e3 = __expf(v3 - m), e4 = __expf(v4 - m);
    const float inv = __fdividef(1.0f, e0 + e1 + e2 + e3 + e4);
    float* o = out + (size_t)(row0 + tid) * 5;
    o[0] = e0 * inv; o[1] = e1 * inv; o[2] = e2 * inv; o[3] = e3 * inv; o[4] = e4 * inv;
  }
}

extern "C" void kernel_launch(void* const* d_in, const int* in_sizes, int n_in,
                              void* d_out, int out_size, void* d_ws, size_t ws_size,
                              hipStream_t stream) {
  (void)in_sizes; (void)n_in; (void)d_ws; (void)ws_size; (void)out_size;
  lstm_f16reg_kernel<<<dim3(256), dim3(kThr), 0, stream>>>(
      (const float*)d_in[0],
      (const float*)d_in[1], (const float*)d_in[2],
      (const float*)d_in[3], (const float*)d_in[4],
      (const float*)d_in[5], (const float*)d_in[6],
      (const float*)d_in[7], (const float*)d_in[8],
      (const float*)d_in[9], (const float*)d_in[10],
      (float*)d_out);
}

// Round 6
// 592.899 us; speedup vs baseline: 110.1069x; 2.0876x over previous
//
#include <hip/hip_runtime.h>

// Persistent fused 2-layer LSTM + FC + softmax for MI355X (gfx950).
// B=2048, T=256, H=64, IN=42. 256 blocks x 256 threads; block owns 8 rows.
//
// R5 lesson: dot2-based GEMM is VALU-instruction bound (~7K busy cyc/step).
// R6: MFMA. Per step, gates = A[16m x 128k] * B[128k x 256n] via
// mfma_f32_16x16x32_f16 (f16 operands, fp32 accum — same numerics as R5).
// Wave w owns h-slice [16w,16w+16) = gate tiles {w,w+4,w+8,w+12}, so each
// lane's 4 accumulators are the i,f,g,o of ONE (m,h) cell -> LSTM update is
// fully in-register (c-state per lane); no gate matrix round-trip in LDS.
// Weights live in VGPRs as B-fragments (loaded once, 128 VGPRs; budget 512
// at 1 wave/SIMD). LDS holds only h/x rows as f16, row stride 136 so
// A-fragments are contiguous b128 reads. M=8 real rows padded to 16
// (quads 2,3 produce garbage rows, masked off in the update).

typedef _Float16 f16;
typedef _Float16 f16x2 __attribute__((ext_vector_type(2)));
typedef _Float16 f16x8 __attribute__((ext_vector_type(8)));
typedef float f32x4 __attribute__((ext_vector_type(4)));

namespace {
constexpr int kT = 256;
constexpr int kIn = 42;
constexpr int kH = 64;
constexpr int kRows = 8;    // real batch rows per block
constexpr int kThr = 256;
constexpr int kKP = 136;    // LDS row stride in f16 (128 + 8 pad; 272 B)
}

__device__ __forceinline__ float sig_(float v) {
  return __fdividef(1.0f, 1.0f + __expf(-v));
}
__device__ __forceinline__ float tnh_(float v) {
  return __fdividef(2.0f, 1.0f + __expf(-2.0f * v)) - 1.0f;
}

__global__ __launch_bounds__(kThr, 1)
void lstm_mfma_kernel(const float* __restrict__ x,
                      const float* __restrict__ Wih0, const float* __restrict__ Whh0,
                      const float* __restrict__ bih0, const float* __restrict__ bhh0,
                      const float* __restrict__ Wih1, const float* __restrict__ Whh1,
                      const float* __restrict__ bih1, const float* __restrict__ bhh1,
                      const float* __restrict__ Wfc, const float* __restrict__ bfc,
                      float* __restrict__ out) {
  // xh0 row m: [ x(t) (42) | h0 (64) | pad ] ; xh1 row m: [ h0 (64) | h1 (64) | pad ]
  __shared__ __align__(16) f16 xh0[16 * kKP];
  __shared__ __align__(16) f16 xh1[16 * kKP];
  __shared__ float lg[kRows * 8];

  const int tid = threadIdx.x;
  const int w = tid >> 6;        // wave 0..3  -> h-slice [16w, 16w+16)
  const int l = tid & 63;
  const int c = l & 15;          // MFMA col lane / A-row m
  const int quad = l >> 4;       // 0..3
  const int row0 = blockIdx.x * kRows;

  for (int i = tid; i < 16 * kKP; i += kThr) { xh0[i] = (f16)0; xh1[i] = (f16)0; }

  // ---- one-time: weights as MFMA B-fragments, biases ----
  // tile a: gates g = (w + 4a)*16 + c  (a=0:i, 1:f, 2:g, 3:o for h-dim 16w+c)
  // B-frag lane layout (16x16x32): B[k = q*32 + quad*8 + j][n = c]
  f16x8 B0[4][4], B1[4][4];
  float bias0[4], bias1[4];
#pragma unroll
  for (int a = 0; a < 4; ++a) {
    const int g = (w + 4 * a) * 16 + c;
    bias0[a] = bih0[g] + bhh0[g];
    bias1[a] = bih1[g] + bhh1[g];
#pragma unroll
    for (int q = 0; q < 4; ++q) {
      f16x8 v0, v1;
#pragma unroll
      for (int j = 0; j < 8; ++j) {
        const int k = q * 32 + quad * 8 + j;
        const float w0v = (k < 42) ? Wih0[g * kIn + k]
                        : (k < 106) ? Whh0[g * kH + (k - 42)] : 0.f;
        const float w1v = (k < 64) ? Wih1[g * kH + k] : Whh1[g * kH + (k - 64)];
        v0[j] = (f16)w0v;
        v1[j] = (f16)w1v;
      }
      B0[a][q] = v0;
      B1[a][q] = v1;
    }
  }

  // per-lane cell state for rows m = quad*4+i (real only when quad<2), h = 16w+c
  float c0s[4] = {0.f, 0.f, 0.f, 0.f};
  float c1s[4] = {0.f, 0.f, 0.f, 0.f};
  const int hcol = w * 16 + c;

  const float* xbase = x + (size_t)row0 * kT * kIn;
  const int srr = tid / 21, sp = tid - srr * 21;  // x staging role (tid<168)

  // stage x(0)
  if (tid < 168) {
    const float2 v = *(const float2*)(xbase + (size_t)srr * kT * kIn + 2 * sp);
    f16x2 hv; hv.x = (f16)v.x; hv.y = (f16)v.y;
    *(f16x2*)&xh0[srr * kKP + 2 * sp] = hv;
  }
  __syncthreads();

  for (int t = 0; t < kT; ++t) {
    // prefetch x(t+1) into regs (written to LDS after barrier B)
    float2 xv;
    const bool havex = (t + 1 < kT) && (tid < 168);
    if (havex)
      xv = *(const float2*)(xbase + (size_t)srr * kT * kIn + (size_t)(t + 1) * kIn + 2 * sp);

    // ---------------- layer 0 ----------------
    f16x8 A0[4];
    {
      const f16* ar = xh0 + c * kKP + quad * 8;
#pragma unroll
      for (int q = 0; q < 4; ++q)
        A0[q] = __builtin_bit_cast(f16x8, *(const float4*)(ar + q * 32));
    }
    f32x4 acc[4];
#pragma unroll
    for (int a = 0; a < 4; ++a) acc[a] = (f32x4){bias0[a], bias0[a], bias0[a], bias0[a]};
#pragma unroll
    for (int q = 0; q < 4; ++q) {
#pragma unroll
      for (int a = 0; a < 4; ++a)
        acc[a] = __builtin_amdgcn_mfma_f32_16x16x32_f16(A0[q], B0[a][q], acc[a], 0, 0, 0);
    }
    float h0v[4];
    if (quad < 2) {
#pragma unroll
      for (int i = 0; i < 4; ++i) {
        const float gi = acc[0][i], gf = acc[1][i], gg = acc[2][i], go = acc[3][i];
        c0s[i] = sig_(gf) * c0s[i] + sig_(gi) * tnh_(gg);
        h0v[i] = sig_(go) * tnh_(c0s[i]);
      }
    }
    __syncthreads();  // A: all waves' xh0 A-reads done (WAR for h0/x writes)
    if (quad < 2) {
#pragma unroll
      for (int i = 0; i < 4; ++i) {
        const int m = quad * 4 + i;
        const f16 hv = (f16)h0v[i];
        xh0[m * kKP + 42 + hcol] = hv;   // for next step's layer 0
        xh1[m * kKP + hcol] = hv;        // for this step's layer 1
      }
    }
    if (havex) {
      f16x2 hv; hv.x = (f16)xv.x; hv.y = (f16)xv.y;
      *(f16x2*)&xh0[srr * kKP + 2 * sp] = hv;
    }
    __syncthreads();  // B: h0 (and x(t+1)) visible

    // ---------------- layer 1 ----------------
    f16x8 A1[4];
    {
      const f16* ar = xh1 + c * kKP + quad * 8;
#pragma unroll
      for (int q = 0; q < 4; ++q)
        A1[q] = __builtin_bit_cast(f16x8, *(const float4*)(ar + q * 32));
    }
#pragma unroll
    for (int a = 0; a < 4; ++a) acc[a] = (f32x4){bias1[a], bias1[a], bias1[a], bias1[a]};
#pragma unroll
    for (int q = 0; q < 4; ++q) {
#pragma unroll
      for (int a = 0; a < 4; ++a)
        acc[a] = __builtin_amdgcn_mfma_f32_16x16x32_f16(A1[q], B1[a][q], acc[a], 0, 0, 0);
    }
    float h1v[4];
    if (quad < 2) {
#pragma unroll
      for (int i = 0; i < 4; ++i) {
        const float gi = acc[0][i], gf = acc[1][i], gg = acc[2][i], go = acc[3][i];
        c1s[i] = sig_(gf) * c1s[i] + sig_(gi) * tnh_(gg);
        h1v[i] = sig_(go) * tnh_(c1s[i]);
      }
    }
    __syncthreads();  // C: all waves' xh1 A-reads done (WAR for h1 writes)
    if (quad < 2) {
#pragma unroll
      for (int i = 0; i < 4; ++i) {
        const int m = quad * 4 + i;
        xh1[m * kKP + 64 + hcol] = (f16)h1v[i];
      }
    }
    __syncthreads();  // D: h1 visible for next step
  }

  // ---------------- FC + softmax (final h1 in xh1[m][64..127]) ----------------
  if (tid < kRows * 5) {
    const int rr = tid / 5, oo = tid - rr * 5;
    float a = bfc[oo];
#pragma unroll
    for (int j = 0; j < kH; ++j)
      a += (float)xh1[rr * kKP + 64 + j] * Wfc[oo * kH + j];
    lg[rr * 8 + oo] = a;
  }
  __syncthreads();
  if (tid < kRows) {
    const float v0 = lg[tid * 8 + 0], v1 = lg[tid * 8 + 1], v2 = lg[tid * 8 + 2],
                v3 = lg[tid * 8 + 3], v4 = lg[tid * 8 + 4];
    const float m = fmaxf(fmaxf(fmaxf(v0, v1), fmaxf(v2, v3)), v4);
    const float e0 = __expf(v0 - m), e1 = __expf(v1 - m), e2 = __expf(v2 - m),
                e3 = __expf(v3 - m), e4 = __expf(v4 - m);
    const float inv = __fdividef(1.0f, e0 + e1 + e2 + e3 + e4);
    float* o = out + (size_t)(row0 + tid) * 5;
    o[0] = e0 * inv; o[1] = e1 * inv; o[2] = e2 * inv; o[3] = e3 * inv; o[4] = e4 * inv;
  }
}

extern "C" void kernel_launch(void* const* d_in, const int* in_sizes, int n_in,
                              void* d_out, int out_size, void* d_ws, size_t ws_size,
                              hipStream_t stream) {
  (void)in_sizes; (void)n_in; (void)d_ws; (void)ws_size; (void)out_size;
  lstm_mfma_kernel<<<dim3(256), dim3(kThr), 0, stream>>>(
      (const float*)d_in[0],
      (const float*)d_in[1], (const float*)d_in[2],
      (const float*)d_in[3], (const float*)d_in[4],
      (const float*)d_in[5], (const float*)d_in[6],
      (const float*)d_in[7], (const float*)d_in[8],
      (const float*)d_in[9], (const float*)d_in[10],
      (float*)d_out);
}

// Round 7
// 538.588 us; speedup vs baseline: 121.2100x; 1.1008x over previous
//
#include <hip/hip_runtime.h>

// Persistent fused 2-layer LSTM + FC + softmax for MI355X (gfx950).
// B=2048, T=256, H=64, IN=42. 256 blocks x 512 threads; block owns 8 rows.
//
// R6 lesson: 4 barriers/step at 1 wave/SIMD exposes every chain latency
// (4800 cyc/step vs 155 cyc MFMA). R7: wave-specialized layer pipeline —
// waves 0-3 compute layer0(step i) while waves 4-7 compute layer1(step i-1)
// (legal: layer0(t+1) needs only h0(t),x; layer1(t) needs h0(t),h1(t-1)).
// 2 waves/SIMD fill each other's stalls; 2 barriers/step total; per-wave
// MFMA=16, per-lane transcendentals halved; weights per wave = 64 VGPRs.
// Same MFMA f16/fp32 numerics as R6 (absmax 9.8e-4).

typedef _Float16 f16;
typedef _Float16 f16x2 __attribute__((ext_vector_type(2)));
typedef _Float16 f16x8 __attribute__((ext_vector_type(8)));
typedef float f32x4 __attribute__((ext_vector_type(4)));

namespace {
constexpr int kT = 256;
constexpr int kIn = 42;
constexpr int kH = 64;
constexpr int kRows = 8;
constexpr int kThr = 512;
constexpr int kKP = 136;    // LDS row stride in f16 (272 B)
}

__device__ __forceinline__ float sig_(float v) {
  return __fdividef(1.0f, 1.0f + __expf(-v));
}
__device__ __forceinline__ float tnh_(float v) {
  return __fdividef(2.0f, 1.0f + __expf(-2.0f * v)) - 1.0f;
}

__global__ __launch_bounds__(kThr, 2)
void lstm_ws_kernel(const float* __restrict__ x,
                    const float* __restrict__ Wih0, const float* __restrict__ Whh0,
                    const float* __restrict__ bih0, const float* __restrict__ bhh0,
                    const float* __restrict__ Wih1, const float* __restrict__ Whh1,
                    const float* __restrict__ bih1, const float* __restrict__ bhh1,
                    const float* __restrict__ Wfc, const float* __restrict__ bfc,
                    float* __restrict__ out) {
  // xh0 row m: [ x(t) (42) | h0 (64) | pad ]  (read by group A)
  // xh1 row m: [ h0 (64) | h1 (64) | pad ]    (read by group B)
  __shared__ __align__(16) f16 xh0[16 * kKP];
  __shared__ __align__(16) f16 xh1[16 * kKP];
  __shared__ float lg[kRows * 8];

  const int tid = threadIdx.x;
  const int w8 = tid >> 6;
  const bool isA = (w8 < 4);     // group A: layer 0; group B: layer 1
  const int w = w8 & 3;          // h-slice [16w, 16w+16)
  const int l = tid & 63;
  const int c = l & 15;
  const int quad = l >> 4;
  const int row0 = blockIdx.x * kRows;

  for (int i = tid; i < 16 * kKP; i += kThr) { xh0[i] = (f16)0; xh1[i] = (f16)0; }

  // ---- one-time: this group's weights as MFMA B-fragments + biases ----
  // tile a: gate rows g = (w+4a)*16 + c; B[k=q*32+quad*8+j][n=c]
  f16x8 Bw[4][4];
  float bias[4];
#pragma unroll
  for (int a = 0; a < 4; ++a) {
    const int g = (w + 4 * a) * 16 + c;
    bias[a] = isA ? (bih0[g] + bhh0[g]) : (bih1[g] + bhh1[g]);
#pragma unroll
    for (int q = 0; q < 4; ++q) {
      f16x8 v;
#pragma unroll
      for (int j = 0; j < 8; ++j) {
        const int k = q * 32 + quad * 8 + j;
        float wv;
        if (isA)
          wv = (k < 42) ? Wih0[g * kIn + k] : (k < 106) ? Whh0[g * kH + (k - 42)] : 0.f;
        else
          wv = (k < 64) ? Wih1[g * kH + k] : Whh1[g * kH + (k - 64)];
        v[j] = (f16)wv;
      }
      Bw[a][q] = v;
    }
  }

  // cell state: c0 (A waves) or c1 (B waves) for rows m=quad*4+i (quad<2)
  float cst[4] = {0.f, 0.f, 0.f, 0.f};
  const int hcol = w * 16 + c;

  // x staging: 168 group-B threads, one float2 each
  const float* xbase = x + (size_t)row0 * kT * kIn;
  const int stid = tid - 256;
  const bool stager = (!isA) && (stid < 168);
  const int srr = stager ? stid / 21 : 0;
  const int sp = stager ? stid - srr * 21 : 0;

  if (stager) {  // pre-stage x(0)
    const float2 v = *(const float2*)(xbase + (size_t)srr * kT * kIn + 2 * sp);
    f16x2 hv; hv.x = (f16)v.x; hv.y = (f16)v.y;
    *(f16x2*)&xh0[srr * kKP + 2 * sp] = hv;
  }
  __syncthreads();

  // iteration i: group A computes layer0(t=i), group B computes layer1(t=i-1)
  for (int i = 0; i <= kT; ++i) {
    const bool act = isA ? (i < kT) : (i > 0);

    float2 xv;
    const bool havex = stager && (i + 1 < kT);
    if (havex)
      xv = *(const float2*)(xbase + (size_t)srr * kT * kIn + (size_t)(i + 1) * kIn + 2 * sp);

    float hv_[4];
    if (act) {
      const f16* ar = (isA ? xh0 : xh1) + c * kKP + quad * 8;
      f16x8 A[4];
#pragma unroll
      for (int q = 0; q < 4; ++q)
        A[q] = __builtin_bit_cast(f16x8, *(const float4*)(ar + q * 32));
      f32x4 acc[4];
#pragma unroll
      for (int a = 0; a < 4; ++a) acc[a] = (f32x4){bias[a], bias[a], bias[a], bias[a]};
#pragma unroll
      for (int q = 0; q < 4; ++q) {
#pragma unroll
        for (int a = 0; a < 4; ++a)
          acc[a] = __builtin_amdgcn_mfma_f32_16x16x32_f16(A[q], Bw[a][q], acc[a], 0, 0, 0);
      }
      if (quad < 2) {
#pragma unroll
        for (int i4 = 0; i4 < 4; ++i4) {
          const float gi = acc[0][i4], gf = acc[1][i4], gg = acc[2][i4], go = acc[3][i4];
          cst[i4] = sig_(gf) * cst[i4] + sig_(gi) * tnh_(gg);
          hv_[i4] = sig_(go) * tnh_(cst[i4]);
        }
      }
    }
    __syncthreads();  // 1: all A-fragment reads done (WAR)

    if (act && quad < 2) {
#pragma unroll
      for (int i4 = 0; i4 < 4; ++i4) {
        const int m = quad * 4 + i4;
        const f16 h = (f16)hv_[i4];
        if (isA) {
          xh0[m * kKP + 42 + hcol] = h;   // for A's next step
          xh1[m * kKP + hcol] = h;        // for B's next iteration
        } else {
          xh1[m * kKP + 64 + hcol] = h;   // h1 recurrent input
        }
      }
    }
    if (havex) {
      f16x2 hv; hv.x = (f16)xv.x; hv.y = (f16)xv.y;
      *(f16x2*)&xh0[srr * kKP + 2 * sp] = hv;
    }
    __syncthreads();  // 2: writes visible
  }

  // ---- FC + softmax (final h1(T-1) in xh1[m][64..127]) ----
  if (tid < kRows * 5) {
    const int rr = tid / 5, oo = tid - rr * 5;
    float a = bfc[oo];
#pragma unroll
    for (int j = 0; j < kH; ++j)
      a += (float)xh1[rr * kKP + 64 + j] * Wfc[oo * kH + j];
    lg[rr * 8 + oo] = a;
  }
  __syncthreads();
  if (tid < kRows) {
    const float v0 = lg[tid * 8 + 0], v1 = lg[tid * 8 + 1], v2 = lg[tid * 8 + 2],
                v3 = lg[tid * 8 + 3], v4 = lg[tid * 8 + 4];
    const float m = fmaxf(fmaxf(fmaxf(v0, v1), fmaxf(v2, v3)), v4);
    const float e0 = __expf(v0 - m), e1 = __expf(v1 - m), e2 = __expf(v2 - m),
                e3 = __expf(v3 - m), e4 = __expf(v4 - m);
    const float inv = __fdividef(1.0f, e0 + e1 + e2 + e3 + e4);
    float* o = out + (size_t)(row0 + tid) * 5;
    o[0] = e0 * inv; o[1] = e1 * inv; o[2] = e2 * inv; o[3] = e3 * inv; o[4] = e4 * inv;
  }
}

extern "C" void kernel_launch(void* const* d_in, const int* in_sizes, int n_in,
                              void* d_out, int out_size, void* d_ws, size_t ws_size,
                              hipStream_t stream) {
  (void)in_sizes; (void)n_in; (void)d_ws; (void)ws_size; (void)out_size;
  lstm_ws_kernel<<<dim3(256), dim3(kThr), 0, stream>>>(
      (const float*)d_in[0],
      (const float*)d_in[1], (const float*)d_in[2],
      (const float*)d_in[3], (const float*)d_in[4],
      (const float*)d_in[5], (const float*)d_in[6],
      (const float*)d_in[7], (const float*)d_in[8],
      (const float*)d_in[9], (const float*)d_in[10],
      (float*)d_out);
}

// Round 8
// 385.101 us; speedup vs baseline: 169.5199x; 1.3986x over previous
//
#include <hip/hip_runtime.h>

// Persistent fused 2-layer LSTM + FC + softmax for MI355X (gfx950).
// B=2048, T=256, H=64, IN=42. 256 blocks x 512 threads; block owns 8 rows.
// Waves 0-3: layer0(step i); waves 4-7: layer1(step i-1)  (R7 pipeline).
//
// R8 changes:
// 1) Interleaved row map m = (r>>1)*4 + (r&1): real cells land at acc idx
//    i in {0,1} for EVERY quad -> all 64 lanes update exactly 2 cells
//    (R7: half the lanes, 4 cells each) -> quarter-rate activation issue
//    per wave halves; zero divergence. Pure permutation, same numerics.
// 2) Ping-pong LDS slots (read cur / write nxt) -> 1 barrier per iteration
//    instead of 2 (no WAR hazard inside an iteration).

typedef _Float16 f16;
typedef _Float16 f16x2 __attribute__((ext_vector_type(2)));
typedef _Float16 f16x8 __attribute__((ext_vector_type(8)));
typedef float f32x4 __attribute__((ext_vector_type(4)));

namespace {
constexpr int kT = 256;
constexpr int kIn = 42;
constexpr int kH = 64;
constexpr int kRows = 8;
constexpr int kThr = 512;
constexpr int kKP = 136;          // LDS row stride in f16 (272 B)
constexpr int kSlot = 16 * kKP;   // one ping-pong slot (f16 elems)
}

__device__ __forceinline__ float sig_(float v) {
  return __fdividef(1.0f, 1.0f + __expf(-v));
}
__device__ __forceinline__ float tnh_(float v) {
  return __fdividef(2.0f, 1.0f + __expf(-2.0f * v)) - 1.0f;
}

__global__ __launch_bounds__(kThr, 2)
void lstm_pp_kernel(const float* __restrict__ x,
                    const float* __restrict__ Wih0, const float* __restrict__ Whh0,
                    const float* __restrict__ bih0, const float* __restrict__ bhh0,
                    const float* __restrict__ Wih1, const float* __restrict__ Whh1,
                    const float* __restrict__ bih1, const float* __restrict__ bhh1,
                    const float* __restrict__ Wfc, const float* __restrict__ bfc,
                    float* __restrict__ out) {
  // xh0 row m: [ x(t) (42) | h0 (64) | pad ]   (group A reads)
  // xh1 row m: [ h0 (64) | h1 (64) | pad ]     (group B reads)
  __shared__ __align__(16) f16 xh0[2 * kSlot];
  __shared__ __align__(16) f16 xh1[2 * kSlot];
  __shared__ float lg[kRows * 8];

  const int tid = threadIdx.x;
  const int w8 = tid >> 6;
  const bool isA = (w8 < 4);     // A: layer 0; B: layer 1
  const int w = w8 & 3;          // h-slice [16w, 16w+16)
  const int l = tid & 63;
  const int c = l & 15;
  const int quad = l >> 4;
  const int row0 = blockIdx.x * kRows;

  for (int i = tid; i < 2 * kSlot; i += kThr) { xh0[i] = (f16)0; xh1[i] = (f16)0; }

  // ---- one-time: this group's weights as MFMA B-fragments + biases ----
  f16x8 Bw[4][4];
  float bias[4];
#pragma unroll
  for (int a = 0; a < 4; ++a) {
    const int g = (w + 4 * a) * 16 + c;
    bias[a] = isA ? (bih0[g] + bhh0[g]) : (bih1[g] + bhh1[g]);
#pragma unroll
    for (int q = 0; q < 4; ++q) {
      f16x8 v;
#pragma unroll
      for (int j = 0; j < 8; ++j) {
        const int k = q * 32 + quad * 8 + j;
        float wv;
        if (isA)
          wv = (k < 42) ? Wih0[g * kIn + k] : (k < 106) ? Whh0[g * kH + (k - 42)] : 0.f;
        else
          wv = (k < 64) ? Wih1[g * kH + k] : Whh1[g * kH + (k - 64)];
        v[j] = (f16)wv;
      }
      Bw[a][q] = v;
    }
  }

  // Each lane owns cells (m = quad*4 + i, i in {0,1}) -> batch row
  // r = quad*2 + i (interleaved map m = (r>>1)*4 + (r&1)). State per lane:
  float cst[2] = {0.f, 0.f};
  const int hcol = w * 16 + c;

  // x staging: 168 group-B threads, one float2 each; row r -> LDS row m(r)
  const float* xbase = x + (size_t)row0 * kT * kIn;
  const int stid = tid - 256;
  const bool stager = (!isA) && (stid < 168);
  const int srr = stager ? stid / 21 : 0;
  const int sp = stager ? stid - srr * 21 : 0;
  const int sm = ((srr >> 1) << 2) | (srr & 1);   // LDS row for batch row srr

  if (stager) {  // pre-stage x(0) into slot 0
    const float2 v = *(const float2*)(xbase + (size_t)srr * kT * kIn + 2 * sp);
    f16x2 hv; hv.x = (f16)v.x; hv.y = (f16)v.y;
    *(f16x2*)&xh0[sm * kKP + 2 * sp] = hv;
  }
  __syncthreads();

  // iter i: A computes layer0(t=i), B computes layer1(t=i-1)
  for (int i = 0; i <= kT; ++i) {
    const int cur = i & 1, nxt = cur ^ 1;
    const bool act = isA ? (i < kT) : (i > 0);

    float2 xv;
    const bool havex = stager && (i + 1 < kT);
    if (havex)
      xv = *(const float2*)(xbase + (size_t)srr * kT * kIn + (size_t)(i + 1) * kIn + 2 * sp);

    float hv_[2];
    if (act) {
      const f16* ar = (isA ? xh0 : xh1) + cur * kSlot + c * kKP + quad * 8;
      f16x8 A[4];
#pragma unroll
      for (int q = 0; q < 4; ++q)
        A[q] = __builtin_bit_cast(f16x8, *(const float4*)(ar + q * 32));
      f32x4 acc[4];
#pragma unroll
      for (int a = 0; a < 4; ++a) acc[a] = (f32x4){bias[a], bias[a], bias[a], bias[a]};
#pragma unroll
      for (int q = 0; q < 4; ++q) {
#pragma unroll
        for (int a = 0; a < 4; ++a)
          acc[a] = __builtin_amdgcn_mfma_f32_16x16x32_f16(A[q], Bw[a][q], acc[a], 0, 0, 0);
      }
      // cells i2 = 0,1 are real for every quad (interleaved row map)
#pragma unroll
      for (int i2 = 0; i2 < 2; ++i2) {
        const float gi = acc[0][i2], gf = acc[1][i2], gg = acc[2][i2], go = acc[3][i2];
        cst[i2] = sig_(gf) * cst[i2] + sig_(gi) * tnh_(gg);
        hv_[i2] = sig_(go) * tnh_(cst[i2]);
      }
      // write to nxt slot (no WAR hazard: nobody reads nxt this iteration)
#pragma unroll
      for (int i2 = 0; i2 < 2; ++i2) {
        const int m = quad * 4 + i2;
        const f16 h = (f16)hv_[i2];
        if (isA) {
          xh0[nxt * kSlot + m * kKP + 42 + hcol] = h;  // A's next step
          xh1[nxt * kSlot + m * kKP + hcol] = h;       // B's next iteration
        } else {
          xh1[nxt * kSlot + m * kKP + 64 + hcol] = h;  // h1 recurrent input
        }
      }
    }
    if (havex) {
      f16x2 hv; hv.x = (f16)xv.x; hv.y = (f16)xv.y;
      *(f16x2*)&xh0[nxt * kSlot + sm * kKP + 2 * sp] = hv;
    }
    __syncthreads();  // publish nxt-slot writes; next iter reads them as cur
  }

  // ---- FC + softmax. Final h1(T-1) is in slot (kT&1)^1 = 1. ----
  if (tid < kRows * 5) {
    const int rr = tid / 5, oo = tid - rr * 5;
    const int m = ((rr >> 1) << 2) | (rr & 1);
    float a = bfc[oo];
#pragma unroll
    for (int j = 0; j < kH; ++j)
      a += (float)xh1[kSlot + m * kKP + 64 + j] * Wfc[oo * kH + j];
    lg[rr * 8 + oo] = a;
  }
  __syncthreads();
  if (tid < kRows) {
    const float v0 = lg[tid * 8 + 0], v1 = lg[tid * 8 + 1], v2 = lg[tid * 8 + 2],
                v3 = lg[tid * 8 + 3], v4 = lg[tid * 8 + 4];
    const float m = fmaxf(fmaxf(fmaxf(v0, v1), fmaxf(v2, v3)), v4);
    const float e0 = __expf(v0 - m), e1 = __expf(v1 - m), e2 = __expf(v2 - m),
                e3 = __expf(v3 - m), e4 = __expf(v4 - m);
    const float inv = __fdividef(1.0f, e0 + e1 + e2 + e3 + e4);
    float* o = out + (size_t)(row0 + tid) * 5;
    o[0] = e0 * inv; o[1] = e1 * inv; o[2] = e2 * inv; o[3] = e3 * inv; o[4] = e4 * inv;
  }
}

extern "C" void kernel_launch(void* const* d_in, const int* in_sizes, int n_in,
                              void* d_out, int out_size, void* d_ws, size_t ws_size,
                              hipStream_t stream) {
  (void)in_sizes; (void)n_in; (void)d_ws; (void)ws_size; (void)out_size;
  lstm_pp_kernel<<<dim3(256), dim3(kThr), 0, stream>>>(
      (const float*)d_in[0],
      (const float*)d_in[1], (const float*)d_in[2],
      (const float*)d_in[3], (const float*)d_in[4],
      (const float*)d_in[5], (const float*)d_in[6],
      (const float*)d_in[7], (const float*)d_in[8],
      (const float*)d_in[9], (const float*)d_in[10],
      (float*)d_out);
}